// Round 2
// baseline (146486.230 us; speedup 1.0000x reference)
//
#include <hip/hip_runtime.h>
#include <hip/hip_bf16.h>

// MultilayerGRU: B=32 S=512 I=H=O=1024 L=3.
// Round 2: dtype-adaptive (fp32 vs bf16 decided on-device from x's bit
// patterns), fp32 recurrence, per-(step,layer) kernels, deferred output GEMM
// in place on d_out over the stashed h2 history.

#define NB 32
#define NS 512
#define NI 1024
#define NH 1024
#define NL 3
#define NO 1024
#define FLAG_OFF (2 * NL * NB * NH)   // flag location in ws, float units

static __device__ __forceinline__ float bf2f(unsigned short u) {
    union { unsigned int i; float f; } v;
    v.i = ((unsigned int)u) << 16;
    return v.f;
}

static __device__ __forceinline__ unsigned short f2bf(float f) {
    __hip_bfloat16 h = __float2bfloat16(f);   // RNE
    union { __hip_bfloat16 h; unsigned short u; } v;
    v.h = h;
    return v.u;
}

static __device__ __forceinline__ void load8h(const unsigned short* p, float w[8]) {
    uint4 q = *(const uint4*)p;
    unsigned int u[4] = {q.x, q.y, q.z, q.w};
#pragma unroll
    for (int i = 0; i < 4; ++i) {
        w[2*i]   = __uint_as_float(u[i] << 16);
        w[2*i+1] = __uint_as_float(u[i] & 0xffff0000u);
    }
}

static __device__ __forceinline__ void load8f(const float* p, float w[8]) {
    float4 a = *(const float4*)p;
    float4 b = *(const float4*)(p + 4);
    w[0]=a.x; w[1]=a.y; w[2]=a.z; w[3]=a.w;
    w[4]=b.x; w[5]=b.y; w[6]=b.z; w[7]=b.w;
}

// flag=1 -> tensors are fp32; flag=0 -> bf16. See analysis: bits 14..7 of a
// word of bf16-packed N(0,1) data are a bf16 exponent (concentrated in
// [0x78,0x84], ~99%); for fp32 data they are uniform mantissa bits (~5%).
__global__ void detect_kernel(const unsigned int* __restrict__ xw, int* __restrict__ flag) {
    __shared__ int cnt[256];
    int c = 0;
    for (int i = threadIdx.x; i < 1024; i += 256) {
        unsigned int e = (xw[i] >> 7) & 0xFFu;
        if (e >= 0x78u && e <= 0x84u) c++;
    }
    cnt[threadIdx.x] = c;
    __syncthreads();
    if (threadIdx.x == 0) {
        int s = 0;
        for (int i = 0; i < 256; ++i) s += cnt[i];
        *flag = (s < 512) ? 1 : 0;
    }
}

__global__ void init_kernel(const void* __restrict__ h0, float* __restrict__ st,
                            const int* __restrict__ flagp) {
    const int f32m = *flagp;
    const int idx = blockIdx.x * 256 + threadIdx.x;   // l*32768 + b*1024 + j
    if (idx >= NL * NB * NH) return;
    const int l = idx >> 15;
    const int b = (idx >> 10) & 31;
    const int j = idx & 1023;
    const size_t src = (size_t)b * NL * NH + (size_t)l * NH + j;
    st[idx] = f32m ? ((const float*)h0)[src] : bf2f(((const unsigned short*)h0)[src]);
}

// grid = 512 blocks (2 output cols each), block = 256: tid = b(32) x jl(2) x ks(4)
__global__ __launch_bounds__(256) void gru_layer(
    const void*  __restrict__ x,
    const float* __restrict__ inp,
    const float* __restrict__ hprev,
    float*       __restrict__ hnew,
    void*        __restrict__ h2out,
    const void* __restrict__ Wzi_, const void* __restrict__ Wzh_, const void* __restrict__ bzh_,
    const void* __restrict__ Wri_, const void* __restrict__ Wrh_, const void* __restrict__ brh_,
    const void* __restrict__ Wgi_, const void* __restrict__ Wgh_, const void* __restrict__ bgh_,
    const int* __restrict__ flagp, int tl, int isX)
{
    __shared__ float s_in[NB][129];
    __shared__ float s_h [NB][129];
    __shared__ float s_red[256][6];

    const int f32m = *flagp;
    const int t = tl & 0xFFFF;
    const int l = tl >> 16;
    const int tid = threadIdx.x;
    const int b   = tid & 31;
    const int jl  = (tid >> 5) & 1;
    const int ks  = tid >> 6;
    const int j   = blockIdx.x * 2 + jl;

    // per-layer element offsets (dtype-independent element counts)
    const size_t wIl = (size_t)l * NH * NI + (size_t)j * NI;  // row j of layer l, input-weights
    const size_t wHl = (size_t)l * NH * NH + (size_t)j * NH;  // row j of layer l, hidden-weights
    const size_t bl  = (size_t)l * NH + j;

    float azi = 0.f, azh = 0.f, ari = 0.f, arh = 0.f, agi = 0.f, agh = 0.f;

    for (int kc = 0; kc < 8; ++kc) {
        const int k0 = kc * 128;
        __syncthreads();
        for (int idx = tid; idx < NB * 128; idx += 256) {
            const int r = idx >> 7, c = idx & 127;
            float vi;
            if (isX) {
                const size_t xo = (size_t)r * NS * NI + (size_t)t * NI + (k0 + c);
                vi = f32m ? ((const float*)x)[xo] : bf2f(((const unsigned short*)x)[xo]);
            } else {
                vi = inp[r * NH + k0 + c];
            }
            s_in[r][c] = vi;
            s_h [r][c] = hprev[r * NH + k0 + c];
        }
        __syncthreads();

        const int cbase = ks * 32;
#pragma unroll
        for (int q8 = 0; q8 < 4; ++q8) {
            const int c = cbase + q8 * 8;
            const int k = k0 + c;
            float wz[8], wr[8], wg[8], vz[8], vr[8], vg[8];
            if (f32m) {
                load8f((const float*)Wzi_ + wIl + k, wz);
                load8f((const float*)Wri_ + wIl + k, wr);
                load8f((const float*)Wgi_ + wIl + k, wg);
                load8f((const float*)Wzh_ + wHl + k, vz);
                load8f((const float*)Wrh_ + wHl + k, vr);
                load8f((const float*)Wgh_ + wHl + k, vg);
            } else {
                load8h((const unsigned short*)Wzi_ + wIl + k, wz);
                load8h((const unsigned short*)Wri_ + wIl + k, wr);
                load8h((const unsigned short*)Wgi_ + wIl + k, wg);
                load8h((const unsigned short*)Wzh_ + wHl + k, vz);
                load8h((const unsigned short*)Wrh_ + wHl + k, vr);
                load8h((const unsigned short*)Wgh_ + wHl + k, vg);
            }
            float ai[8], ah[8];
#pragma unroll
            for (int q = 0; q < 8; ++q) { ai[q] = s_in[b][c + q]; ah[q] = s_h[b][c + q]; }
#pragma unroll
            for (int q = 0; q < 8; ++q) {
                azi = fmaf(wz[q], ai[q], azi);
                ari = fmaf(wr[q], ai[q], ari);
                agi = fmaf(wg[q], ai[q], agi);
                azh = fmaf(vz[q], ah[q], azh);
                arh = fmaf(vr[q], ah[q], arh);
                agh = fmaf(vg[q], ah[q], agh);
            }
        }
    }

    s_red[tid][0] = azi; s_red[tid][1] = azh; s_red[tid][2] = ari;
    s_red[tid][3] = arh; s_red[tid][4] = agi; s_red[tid][5] = agh;
    __syncthreads();

    if (ks == 0) {
#pragma unroll
        for (int w = 1; w < 4; ++w) {
            azi += s_red[tid + 64*w][0]; azh += s_red[tid + 64*w][1];
            ari += s_red[tid + 64*w][2]; arh += s_red[tid + 64*w][3];
            agi += s_red[tid + 64*w][4]; agh += s_red[tid + 64*w][5];
        }
        const float bz = f32m ? ((const float*)bzh_)[bl] : bf2f(((const unsigned short*)bzh_)[bl]);
        const float br = f32m ? ((const float*)brh_)[bl] : bf2f(((const unsigned short*)brh_)[bl]);
        const float bg = f32m ? ((const float*)bgh_)[bl] : bf2f(((const unsigned short*)bgh_)[bl]);
        const float z = 1.f / (1.f + expf(-(azi + azh + bz)));
        const float r = 1.f / (1.f + expf(-(ari + arh + br)));
        const float g = tanhf(agi + r * (agh + bg));
        const float hp = hprev[b * NH + j];
        const float hn = z * hp + (1.f - z) * g;
        hnew[b * NH + j] = hn;
        if (h2out) {
            const size_t off = (size_t)b * NS * NO + (size_t)t * NO + j;
            if (f32m) ((float*)h2out)[off] = hn;
            else      ((unsigned short*)h2out)[off] = f2bf(hn);
        }
    }
}

__global__ __launch_bounds__(256) void out_gemm(
    void* __restrict__ out, const void* __restrict__ Wout, const void* __restrict__ bout,
    const int* __restrict__ flagp)
{
    __shared__ float s_a[8][1024];
    const int f32m = *flagp;
    const int tid = threadIdx.x;
    const size_t row0 = (size_t)blockIdx.x * 8;

    for (int idx = tid; idx < 8 * 1024; idx += 256) {
        const int r = idx >> 10, c = idx & 1023;
        const size_t off = (row0 + r) * NO + c;
        s_a[r][c] = f32m ? ((const float*)out)[off] : bf2f(((const unsigned short*)out)[off]);
    }
    __syncthreads();

    float acc[4][8];
#pragma unroll
    for (int m = 0; m < 4; ++m)
#pragma unroll
        for (int r = 0; r < 8; ++r) acc[m][r] = 0.f;

    for (int k8 = 0; k8 < 128; ++k8) {
        const int k = k8 * 8;
        float wf[4][8];
#pragma unroll
        for (int m = 0; m < 4; ++m) {
            const size_t wo = (size_t)(tid + 256*m) * NH + k;
            if (f32m) load8f((const float*)Wout + wo, wf[m]);
            else      load8h((const unsigned short*)Wout + wo, wf[m]);
        }
#pragma unroll
        for (int r = 0; r < 8; ++r) {
            float a[8];
#pragma unroll
            for (int q = 0; q < 8; ++q) a[q] = s_a[r][k + q];
#pragma unroll
            for (int m = 0; m < 4; ++m)
#pragma unroll
                for (int q = 0; q < 8; ++q)
                    acc[m][r] = fmaf(wf[m][q], a[q], acc[m][r]);
        }
    }

#pragma unroll
    for (int m = 0; m < 4; ++m) {
        const int jj = tid + 256*m;
        const float bj = f32m ? ((const float*)bout)[jj] : bf2f(((const unsigned short*)bout)[jj]);
#pragma unroll
        for (int r = 0; r < 8; ++r) {
            const size_t off = (row0 + r) * NO + jj;
            const float v = acc[m][r] + bj;
            if (f32m) ((float*)out)[off] = v;
            else      ((unsigned short*)out)[off] = f2bf(v);
        }
    }
}

__global__ void tail_kernel(const float* __restrict__ st, void* __restrict__ out,
                            const int* __restrict__ flagp)
{
    const int f32m = *flagp;
    const int idx = blockIdx.x * 256 + threadIdx.x;
    if (idx >= NL * NB * NH) return;
    const int l = idx >> 15;
    const int b = (idx >> 10) & 31;
    const int j = idx & 1023;
    const size_t dst = (size_t)NB * NS * NO + (size_t)b * NL * NH + (size_t)l * NH + j;
    if (f32m) ((float*)out)[dst] = st[idx];
    else      ((unsigned short*)out)[dst] = f2bf(st[idx]);
}

extern "C" void kernel_launch(void* const* d_in, const int* in_sizes, int n_in,
                              void* d_out, int out_size, void* d_ws, size_t ws_size,
                              hipStream_t stream)
{
    const void* x    = d_in[0];
    const void* h0   = d_in[1];
    const void* Wzi  = d_in[2];
    const void* Wzh  = d_in[3];
    const void* bzh  = d_in[4];
    const void* Wri  = d_in[5];
    const void* Wrh  = d_in[6];
    const void* brh  = d_in[7];
    const void* Wgi  = d_in[8];
    const void* Wgh  = d_in[9];
    const void* bgh  = d_in[10];
    const void* Wout = d_in[11];
    const void* bout = d_in[12];

    float* st = (float*)d_ws;                 // [2][L][B][H] fp32 (~768 KB)
    int* flag = (int*)(st + FLAG_OFF);
    auto stp = [&](int p, int l) { return st + ((size_t)(p * NL + l)) * NB * NH; };

    detect_kernel<<<1, 256, 0, stream>>>((const unsigned int*)x, flag);
    init_kernel<<<(NL*NB*NH + 255)/256, 256, 0, stream>>>(h0, st, flag);

    for (int t = 0; t < NS; ++t) {
        const int pr = t & 1, pw = 1 - pr;
        for (int l = 0; l < NL; ++l) {
            gru_layer<<<512, 256, 0, stream>>>(
                x,
                l == 0 ? st : stp(pw, l - 1),
                stp(pr, l),
                stp(pw, l),
                l == 2 ? d_out : (void*)nullptr,
                Wzi, Wzh, bzh, Wri, Wrh, brh, Wgi, Wgh, bgh,
                flag, t | (l << 16), l == 0 ? 1 : 0);
        }
    }

    out_gemm<<<NB * NS / 8, 256, 0, stream>>>(d_out, Wout, bout, flag);
    tail_kernel<<<(NL*NB*NH + 255)/256, 256, 0, stream>>>(st, d_out, flag);
}

// Round 3
// 53917.316 us; speedup vs baseline: 2.7169x; 2.7169x over previous
//
#include <hip/hip_runtime.h>
#include <hip/hip_bf16.h>

// MultilayerGRU: B=32 S=512 I=H=O=1024 L=3.
// Round 3: persistent single-kernel pipeline.
//  - All 37.5 MB of (bf16-converted) weights LDS-resident: 256 WGs x 12
//    columns x 6 rows x 1024 = 147 KB/WG. Grid=256 @ 157 KB LDS -> exactly
//    1 WG/CU, all co-resident -> custom device-scope grid barrier.
//  - Wavefront pipeline over layers: stage s runs layer l at t=s-l.
//    514 stages, 1 grid barrier each (vs 1541 kernel launches before).
//  - Compute via v_mfma_f32_16x16x32_bf16. Activations passed between
//    layers as bf16 hi/lo pairs (exact to 2^-17) in global double buffers.
//  - Gate packing: vcol = col*4 + {z, r, gi, gh}. z/r accumulate i-path and
//    h-path into ONE accumulator; gi/gh stay phase-pure via an LDS zero-row.
//  - Dual-dtype (device tensors fp32 or bf16) via on-device detection.
//  - Full round-2 multi-launch path retained as fallback if the persistent
//    launch is rejected (e.g. LDS size) -- detected with hipGetLastError.

#define NB 32
#define NS 512
#define NI 1024
#define NH 1024
#define NL 3
#define NO 1024

#define WGN 256
#define SLOTS 12
#define RPB 2064                 // weight row pitch bytes (1032 bf16) - 16B aligned, bank-staggered
#define ZROW 72                  // zero-row index
#define COFF (73 * RPB)          // C-region offset = 150,672
#define CPITCH 36                // floats per vcol in C-region (pad 32->36)
#define LDSB (COFF + 48 * CPITCH * 4)   // 157,584 bytes

using short8 = __attribute__((ext_vector_type(8))) short;
using floatx4 = __attribute__((ext_vector_type(4))) float;

static __device__ __forceinline__ float bf2f(unsigned short u) {
    union { unsigned int i; float f; } v;
    v.i = ((unsigned int)u) << 16;
    return v.f;
}

static __device__ __forceinline__ unsigned short f2bf(float f) {
    __hip_bfloat16 h = __float2bfloat16(f);   // RNE
    union { __hip_bfloat16 h; unsigned short u; } v;
    v.h = h;
    return v.u;
}

static __device__ __forceinline__ void load8h(const unsigned short* p, float w[8]) {
    uint4 q = *(const uint4*)p;
    unsigned int u[4] = {q.x, q.y, q.z, q.w};
#pragma unroll
    for (int i = 0; i < 4; ++i) {
        w[2*i]   = __uint_as_float(u[i] << 16);
        w[2*i+1] = __uint_as_float(u[i] & 0xffff0000u);
    }
}

static __device__ __forceinline__ void load8f(const float* p, float w[8]) {
    float4 a = *(const float4*)p;
    float4 b = *(const float4*)(p + 4);
    w[0]=a.x; w[1]=a.y; w[2]=a.z; w[3]=a.w;
    w[4]=b.x; w[5]=b.y; w[6]=b.z; w[7]=b.w;
}

// ---------------- dtype detection ----------------
__global__ void detect_kernel(const unsigned int* __restrict__ xw, int* __restrict__ flag) {
    __shared__ int cnt[256];
    int c = 0;
    for (int i = threadIdx.x; i < 1024; i += 256) {
        unsigned int e = (xw[i] >> 7) & 0xFFu;
        if (e >= 0x78u && e <= 0x84u) c++;
    }
    cnt[threadIdx.x] = c;
    __syncthreads();
    if (threadIdx.x == 0) {
        int s = 0;
        for (int i = 0; i < 256; ++i) s += cnt[i];
        *flag = (s < 512) ? 1 : 0;
    }
}

// ---------------- persistent-path init: h0 -> act[l][1] hi/lo, barrier zero ----
__global__ void init_act(const void* __restrict__ h0,
                         unsigned short* __restrict__ act_hi,
                         unsigned short* __restrict__ act_lo,
                         unsigned int* __restrict__ bar,
                         const int* __restrict__ flagp) {
    const int f32m = *flagp;
    const int idx = blockIdx.x * 256 + threadIdx.x;  // l*32768 + b*1024 + j
    if (idx == 0) { bar[0] = 0u; bar[1] = 0u; }
    if (idx >= NL * NB * NH) return;
    const int l = idx >> 15;
    const int b = (idx >> 10) & 31;
    const int j = idx & 1023;
    const size_t src = (size_t)b * NL * NH + (size_t)l * NH + j;
    float v = f32m ? ((const float*)h0)[src] : bf2f(((const unsigned short*)h0)[src]);
    unsigned short hi = f2bf(v);
    unsigned short lo = f2bf(v - bf2f(hi));
    const size_t dst = ((size_t)(l * 2 + 1) * NB + b) * NH + j;   // parity 1
    act_hi[dst] = hi;
    act_lo[dst] = lo;
}

// ---------------- the persistent pipeline kernel ----------------
__global__ __launch_bounds__(256, 1) void gru_persist(
    const void* __restrict__ x,
    const void* __restrict__ Wzi_, const void* __restrict__ Wzh_, const void* __restrict__ bzh_,
    const void* __restrict__ Wri_, const void* __restrict__ Wrh_, const void* __restrict__ brh_,
    const void* __restrict__ Wgi_, const void* __restrict__ Wgh_, const void* __restrict__ bgh_,
    void* __restrict__ dout,
    unsigned short* __restrict__ act_hi,
    unsigned short* __restrict__ act_lo,
    float* __restrict__ stfin,
    const int* __restrict__ flagp,
    unsigned int* __restrict__ bar)
{
    extern __shared__ char lds[];
    float* clds = (float*)(lds + COFF);

    const int f32m = *flagp;
    const int tid  = threadIdx.x;
    const int wg   = blockIdx.x;
    const int lane = tid & 63;
    const int wid  = tid >> 6;
    const int Mtile = wid & 1;
    const int khalf = wid >> 1;
    const int n16  = lane & 15;
    const int q4   = lane >> 4;

    const int slot0 = wg * SLOTS;

    // ---- preload weights into LDS (bf16) ----
    {
        const void* Wmats[6] = {Wzi_, Wzh_, Wri_, Wrh_, Wgi_, Wgh_};
        if (f32m) {
            for (int idx = tid; idx < 72 * 256; idx += 256) {
                const int r = idx >> 8, c4 = (idx & 255) * 4;
                const int slot = slot0 + r / 6, g = r % 6;
                const int layer = slot >> 10, j = slot & 1023;
                const float* src = (const float*)Wmats[g] + (size_t)layer * NH * NI + (size_t)j * NI + c4;
                float4 f = *(const float4*)src;
                unsigned short* dst = (unsigned short*)(lds + r * RPB + c4 * 2);
                dst[0] = f2bf(f.x); dst[1] = f2bf(f.y); dst[2] = f2bf(f.z); dst[3] = f2bf(f.w);
            }
        } else {
            for (int idx = tid; idx < 72 * 128; idx += 256) {
                const int r = idx >> 7, c8 = (idx & 127) * 8;
                const int slot = slot0 + r / 6, g = r % 6;
                const int layer = slot >> 10, j = slot & 1023;
                const unsigned short* src = (const unsigned short*)Wmats[g] + (size_t)layer * NH * NI + (size_t)j * NI + c8;
                *(uint4*)(lds + r * RPB + c8 * 2) = *(const uint4*)src;
            }
        }
        unsigned short* z = (unsigned short*)(lds + ZROW * RPB);
        for (int c = tid; c < RPB / 2; c += 256) z[c] = 0;
    }

    // ---- layer groups (slots may straddle a layer boundary; boundary is
    //      always 16-vcol aligned since 1024 % 4 == 0) ----
    const int lay0 = slot0 >> 10;
    const int lay1 = (slot0 + SLOTS - 1) >> 10;
    const int ngroups = (lay0 == lay1) ? 1 : 2;
    const int n0 = (ngroups == 1) ? SLOTS : (1024 - (slot0 & 1023));  // slots in group 0

    __syncthreads();

    unsigned int senseExp = 0;

    for (int s = 0; s < NS + NL - 1; ++s) {
        // zero the C staging region
        for (int i = tid; i < 48 * CPITCH; i += 256) clds[i] = 0.f;
        __syncthreads();

        floatx4 acc[3];
#pragma unroll
        for (int nt = 0; nt < 3; ++nt) acc[nt] = (floatx4){0.f, 0.f, 0.f, 0.f};

        for (int grp = 0; grp < ngroups; ++grp) {
            const int lg = (grp == 0) ? lay0 : lay1;
            const int t = s - lg;
            if (t < 0 || t >= NS) continue;
            const int ntLo = (grp == 0) ? 0 : ((4 * n0) >> 4);
            const int ntHi = (grp == 0) ? (ngroups == 1 ? 2 : ((4 * n0) >> 4) - 1) : 2;
            const int mb = Mtile * 16 + n16;        // batch row for A-frags

            for (int phase = 0; phase < 2; ++phase) {
                // B row bases for this phase (per lane, per ntile)
                int brow[3];
#pragma unroll
                for (int nt = 0; nt < 3; ++nt) {
                    const int v = nt * 16 + n16;
                    const int ci = v >> 2, g = v & 3;
                    int r;
                    if (phase == 0) r = (g == 3) ? ZROW : ci * 6 + ((g == 2) ? 4 : g * 2);
                    else            r = (g == 2) ? ZROW : ci * 6 + ((g == 3) ? 5 : g * 2 + 1);
                    brow[nt] = r;
                }

                const bool isx = (phase == 0 && lg == 0);
                const bool dolo = isx ? (f32m != 0) : true;
                const unsigned short* ahb = nullptr;
                const unsigned short* alb = nullptr;
                if (!isx) {
                    const int src_l = (phase == 0) ? lg - 1 : lg;
                    const int src_p = (phase == 0) ? (t & 1) : ((t - 1) & 1);
                    const size_t ab = ((size_t)(src_l * 2 + src_p) * NB) * NH;
                    ahb = act_hi + ab;
                    alb = act_lo + ab;
                }

                for (int ks = 0; ks < 16; ++ks) {
                    const int k0 = khalf * 512 + ks * 32;
                    const int kb = k0 + q4 * 8;
                    short8 ahi, alo;
                    if (isx) {
                        if (f32m) {
                            const float* p = (const float*)x + ((size_t)mb * NS + t) * NI + kb;
                            float f[8];
                            load8f(p, f);
#pragma unroll
                            for (int e = 0; e < 8; ++e) {
                                unsigned short h = f2bf(f[e]);
                                ahi[e] = (short)h;
                                alo[e] = (short)f2bf(f[e] - bf2f(h));
                            }
                        } else {
                            ahi = *(const short8*)((const unsigned short*)x + ((size_t)mb * NS + t) * NI + kb);
                        }
                    } else {
                        const size_t off = (size_t)mb * NH + kb;
                        ahi = *(const short8*)(ahb + off);
                        alo = *(const short8*)(alb + off);
                    }
#pragma unroll
                    for (int nt = 0; nt < 3; ++nt) {
                        if (nt < ntLo || nt > ntHi) continue;
                        const short8 bf = *(const short8*)(lds + brow[nt] * RPB + k0 * 2 + q4 * 16);
                        acc[nt] = __builtin_amdgcn_mfma_f32_16x16x32_bf16(ahi, bf, acc[nt], 0, 0, 0);
                        if (dolo)
                            acc[nt] = __builtin_amdgcn_mfma_f32_16x16x32_bf16(alo, bf, acc[nt], 0, 0, 0);
                    }
                }
            }
        }

        // dump accumulators: C/D layout col=lane&15, row=quad*4+reg
        {
            const int mbase = Mtile * 16 + q4 * 4;
#pragma unroll
            for (int nt = 0; nt < 3; ++nt) {
                const int vcol = nt * 16 + n16;
#pragma unroll
                for (int r = 0; r < 4; ++r)
                    atomicAdd(&clds[vcol * CPITCH + mbase + r], acc[nt][r]);
            }
        }
        __syncthreads();

        // epilogue: 12 cols x 32 batches
        for (int idx = tid; idx < NB * SLOTS; idx += 256) {
            const int ci = idx % SLOTS, b = idx / SLOTS;
            const int slot = slot0 + ci;
            const int lg = slot >> 10, j = slot & 1023;
            const int t = s - lg;
            if (t < 0 || t >= NS) continue;
            const float zp = clds[(ci * 4 + 0) * CPITCH + b];
            const float rp = clds[(ci * 4 + 1) * CPITCH + b];
            const float gi = clds[(ci * 4 + 2) * CPITCH + b];
            const float gh = clds[(ci * 4 + 3) * CPITCH + b];
            const size_t bidx = (size_t)lg * NH + j;
            float bz, br, bg;
            if (f32m) {
                bz = ((const float*)bzh_)[bidx];
                br = ((const float*)brh_)[bidx];
                bg = ((const float*)bgh_)[bidx];
            } else {
                bz = bf2f(((const unsigned short*)bzh_)[bidx]);
                br = bf2f(((const unsigned short*)brh_)[bidx]);
                bg = bf2f(((const unsigned short*)bgh_)[bidx]);
            }
            const size_t hoff = ((size_t)(lg * 2 + ((t - 1) & 1)) * NB + b) * NH + j;
            const float hp = bf2f(act_hi[hoff]) + bf2f(act_lo[hoff]);
            const float z = 1.f / (1.f + expf(-(zp + bz)));
            const float r = 1.f / (1.f + expf(-(rp + br)));
            const float g = tanhf(gi + r * (gh + bg));
            const float hn = z * hp + (1.f - z) * g;
            const unsigned short hi = f2bf(hn);
            const unsigned short lo = f2bf(hn - bf2f(hi));
            const size_t woff = ((size_t)(lg * 2 + (t & 1)) * NB + b) * NH + j;
            act_hi[woff] = hi;
            act_lo[woff] = lo;
            if (lg == 2) {
                const size_t o = ((size_t)b * NS + t) * NO + j;
                if (f32m) ((float*)dout)[o] = hn;
                else      ((unsigned short*)dout)[o] = f2bf(hn);
            }
            if (t == NS - 1)
                stfin[((size_t)lg * NB + b) * NH + j] = hn;
        }

        // ---- grid barrier (sense = monotonically increasing release count) ----
        __syncthreads();
        __threadfence();
        senseExp++;
        if (tid == 0) {
            unsigned int old = atomicAdd(&bar[0], 1u);
            if (old == WGN - 1) {
                __hip_atomic_store(&bar[0], 0u, __ATOMIC_RELAXED, __HIP_MEMORY_SCOPE_AGENT);
                __hip_atomic_fetch_add(&bar[1], 1u, __ATOMIC_RELEASE, __HIP_MEMORY_SCOPE_AGENT);
            }
            while (__hip_atomic_load(&bar[1], __ATOMIC_ACQUIRE, __HIP_MEMORY_SCOPE_AGENT) < senseExp)
                __builtin_amdgcn_s_sleep(1);
        }
        __syncthreads();
    }
}

// ---------------- round-2 fallback kernels (proven correct) ----------------
__global__ void init_kernel(const void* __restrict__ h0, float* __restrict__ st,
                            const int* __restrict__ flagp) {
    const int f32m = *flagp;
    const int idx = blockIdx.x * 256 + threadIdx.x;
    if (idx >= NL * NB * NH) return;
    const int l = idx >> 15;
    const int b = (idx >> 10) & 31;
    const int j = idx & 1023;
    const size_t src = (size_t)b * NL * NH + (size_t)l * NH + j;
    st[idx] = f32m ? ((const float*)h0)[src] : bf2f(((const unsigned short*)h0)[src]);
}

__global__ __launch_bounds__(256) void gru_layer(
    const void*  __restrict__ x,
    const float* __restrict__ inp,
    const float* __restrict__ hprev,
    float*       __restrict__ hnew,
    void*        __restrict__ h2out,
    const void* __restrict__ Wzi_, const void* __restrict__ Wzh_, const void* __restrict__ bzh_,
    const void* __restrict__ Wri_, const void* __restrict__ Wrh_, const void* __restrict__ brh_,
    const void* __restrict__ Wgi_, const void* __restrict__ Wgh_, const void* __restrict__ bgh_,
    const int* __restrict__ flagp, int tl, int isX)
{
    __shared__ float s_in[NB][129];
    __shared__ float s_h [NB][129];
    __shared__ float s_red[256][6];

    const int f32m = *flagp;
    const int t = tl & 0xFFFF;
    const int l = tl >> 16;
    const int tid = threadIdx.x;
    const int b   = tid & 31;
    const int jl  = (tid >> 5) & 1;
    const int ks  = tid >> 6;
    const int j   = blockIdx.x * 2 + jl;

    const size_t wIl = (size_t)l * NH * NI + (size_t)j * NI;
    const size_t bl  = (size_t)l * NH + j;

    float azi = 0.f, azh = 0.f, ari = 0.f, arh = 0.f, agi = 0.f, agh = 0.f;

    for (int kc = 0; kc < 8; ++kc) {
        const int k0 = kc * 128;
        __syncthreads();
        for (int idx = tid; idx < NB * 128; idx += 256) {
            const int r = idx >> 7, c = idx & 127;
            float vi;
            if (isX) {
                const size_t xo = (size_t)r * NS * NI + (size_t)t * NI + (k0 + c);
                vi = f32m ? ((const float*)x)[xo] : bf2f(((const unsigned short*)x)[xo]);
            } else {
                vi = inp[r * NH + k0 + c];
            }
            s_in[r][c] = vi;
            s_h [r][c] = hprev[r * NH + k0 + c];
        }
        __syncthreads();

        const int cbase = ks * 32;
#pragma unroll
        for (int q8 = 0; q8 < 4; ++q8) {
            const int c = cbase + q8 * 8;
            const int k = k0 + c;
            float wz[8], wr[8], wg[8], vz[8], vr[8], vg[8];
            if (f32m) {
                load8f((const float*)Wzi_ + wIl + k, wz);
                load8f((const float*)Wri_ + wIl + k, wr);
                load8f((const float*)Wgi_ + wIl + k, wg);
                load8f((const float*)Wzh_ + wIl + k, vz);
                load8f((const float*)Wrh_ + wIl + k, vr);
                load8f((const float*)Wgh_ + wIl + k, vg);
            } else {
                load8h((const unsigned short*)Wzi_ + wIl + k, wz);
                load8h((const unsigned short*)Wri_ + wIl + k, wr);
                load8h((const unsigned short*)Wgi_ + wIl + k, wg);
                load8h((const unsigned short*)Wzh_ + wIl + k, vz);
                load8h((const unsigned short*)Wrh_ + wIl + k, vr);
                load8h((const unsigned short*)Wgh_ + wIl + k, vg);
            }
            float ai[8], ah[8];
#pragma unroll
            for (int q = 0; q < 8; ++q) { ai[q] = s_in[b][c + q]; ah[q] = s_h[b][c + q]; }
#pragma unroll
            for (int q = 0; q < 8; ++q) {
                azi = fmaf(wz[q], ai[q], azi);
                ari = fmaf(wr[q], ai[q], ari);
                agi = fmaf(wg[q], ai[q], agi);
                azh = fmaf(vz[q], ah[q], azh);
                arh = fmaf(vr[q], ah[q], arh);
                agh = fmaf(vg[q], ah[q], agh);
            }
        }
    }

    s_red[tid][0] = azi; s_red[tid][1] = azh; s_red[tid][2] = ari;
    s_red[tid][3] = arh; s_red[tid][4] = agi; s_red[tid][5] = agh;
    __syncthreads();

    if (ks == 0) {
#pragma unroll
        for (int w = 1; w < 4; ++w) {
            azi += s_red[tid + 64*w][0]; azh += s_red[tid + 64*w][1];
            ari += s_red[tid + 64*w][2]; arh += s_red[tid + 64*w][3];
            agi += s_red[tid + 64*w][4]; agh += s_red[tid + 64*w][5];
        }
        const float bz = f32m ? ((const float*)bzh_)[bl] : bf2f(((const unsigned short*)bzh_)[bl]);
        const float br = f32m ? ((const float*)brh_)[bl] : bf2f(((const unsigned short*)brh_)[bl]);
        const float bg = f32m ? ((const float*)bgh_)[bl] : bf2f(((const unsigned short*)bgh_)[bl]);
        const float z = 1.f / (1.f + expf(-(azi + azh + bz)));
        const float r = 1.f / (1.f + expf(-(ari + arh + br)));
        const float g = tanhf(agi + r * (agh + bg));
        const float hp = hprev[b * NH + j];
        const float hn = z * hp + (1.f - z) * g;
        hnew[b * NH + j] = hn;
        if (h2out) {
            const size_t off = (size_t)b * NS * NO + (size_t)t * NO + j;
            if (f32m) ((float*)h2out)[off] = hn;
            else      ((unsigned short*)h2out)[off] = f2bf(hn);
        }
    }
}

__global__ __launch_bounds__(256) void out_gemm(
    void* __restrict__ out, const void* __restrict__ Wout, const void* __restrict__ bout,
    const int* __restrict__ flagp)
{
    __shared__ float s_a[8][1024];
    const int f32m = *flagp;
    const int tid = threadIdx.x;
    const size_t row0 = (size_t)blockIdx.x * 8;

    for (int idx = tid; idx < 8 * 1024; idx += 256) {
        const int r = idx >> 10, c = idx & 1023;
        const size_t off = (row0 + r) * NO + c;
        s_a[r][c] = f32m ? ((const float*)out)[off] : bf2f(((const unsigned short*)out)[off]);
    }
    __syncthreads();

    float acc[4][8];
#pragma unroll
    for (int m = 0; m < 4; ++m)
#pragma unroll
        for (int r = 0; r < 8; ++r) acc[m][r] = 0.f;

    for (int k8 = 0; k8 < 128; ++k8) {
        const int k = k8 * 8;
        float wf[4][8];
#pragma unroll
        for (int m = 0; m < 4; ++m) {
            const size_t wo = (size_t)(tid + 256*m) * NH + k;
            if (f32m) load8f((const float*)Wout + wo, wf[m]);
            else      load8h((const unsigned short*)Wout + wo, wf[m]);
        }
#pragma unroll
        for (int r = 0; r < 8; ++r) {
            float a[8];
#pragma unroll
            for (int q = 0; q < 8; ++q) a[q] = s_a[r][k + q];
#pragma unroll
            for (int m = 0; m < 4; ++m)
#pragma unroll
                for (int q = 0; q < 8; ++q)
                    acc[m][r] = fmaf(wf[m][q], a[q], acc[m][r]);
        }
    }

#pragma unroll
    for (int m = 0; m < 4; ++m) {
        const int jj = tid + 256*m;
        const float bj = f32m ? ((const float*)bout)[jj] : bf2f(((const unsigned short*)bout)[jj]);
#pragma unroll
        for (int r = 0; r < 8; ++r) {
            const size_t off = (row0 + r) * NO + jj;
            const float v = acc[m][r] + bj;
            if (f32m) ((float*)out)[off] = v;
            else      ((unsigned short*)out)[off] = f2bf(v);
        }
    }
}

__global__ void tail_kernel(const float* __restrict__ st, void* __restrict__ out,
                            const int* __restrict__ flagp)
{
    const int f32m = *flagp;
    const int idx = blockIdx.x * 256 + threadIdx.x;
    if (idx >= NL * NB * NH) return;
    const int l = idx >> 15;
    const int b = (idx >> 10) & 31;
    const int j = idx & 1023;
    const size_t dst = (size_t)NB * NS * NO + (size_t)b * NL * NH + (size_t)l * NH + j;
    if (f32m) ((float*)out)[dst] = st[idx];
    else      ((unsigned short*)out)[dst] = f2bf(st[idx]);
}

// ---------------- host ----------------
extern "C" void kernel_launch(void* const* d_in, const int* in_sizes, int n_in,
                              void* d_out, int out_size, void* d_ws, size_t ws_size,
                              hipStream_t stream)
{
    const void* x    = d_in[0];
    const void* h0   = d_in[1];
    const void* Wzi  = d_in[2];
    const void* Wzh  = d_in[3];
    const void* bzh  = d_in[4];
    const void* Wri  = d_in[5];
    const void* Wrh  = d_in[6];
    const void* brh  = d_in[7];
    const void* Wgi  = d_in[8];
    const void* Wgh  = d_in[9];
    const void* bgh  = d_in[10];
    const void* Wout = d_in[11];
    const void* bout = d_in[12];

    // ws layout
    char* w = (char*)d_ws;
    float* st            = (float*)w;                       // [2][3][32][1024] f32 (fallback + final h at parity 0)
    int*   flag          = (int*)(w + 786432);
    unsigned int* bar    = (unsigned int*)(w + 786440);
    unsigned short* ahi  = (unsigned short*)(w + 786464);   // [3][2][32][1024] bf16
    unsigned short* alo  = ahi + (size_t)NL * 2 * NB * NH;
    auto stp = [&](int p, int l) { return st + ((size_t)(p * NL + l)) * NB * NH; };

    detect_kernel<<<1, 256, 0, stream>>>((const unsigned int*)x, flag);
    init_act<<<(NL*NB*NH + 255)/256, 256, 0, stream>>>(h0, ahi, alo, bar, flag);

    // persistent path
    (void)hipFuncSetAttribute((const void*)gru_persist,
                              hipFuncAttributeMaxDynamicSharedMemorySize, LDSB);
    (void)hipGetLastError();   // clear
    gru_persist<<<WGN, 256, LDSB, stream>>>(
        x, Wzi, Wzh, bzh, Wri, Wrh, brh, Wgi, Wgh, bgh,
        d_out, ahi, alo, st /* final h -> st parity0 */, flag, bar);
    hipError_t perr = hipGetLastError();

    if (perr != hipSuccess) {
        // fallback: round-2 multi-launch path
        init_kernel<<<(NL*NB*NH + 255)/256, 256, 0, stream>>>(h0, st, flag);
        for (int t = 0; t < NS; ++t) {
            const int pr = t & 1, pw = 1 - pr;
            for (int l = 0; l < NL; ++l) {
                gru_layer<<<512, 256, 0, stream>>>(
                    x,
                    l == 0 ? st : stp(pw, l - 1),
                    stp(pr, l),
                    stp(pw, l),
                    l == 2 ? d_out : (void*)nullptr,
                    Wzi, Wzh, bzh, Wri, Wrh, brh, Wgi, Wgh, bgh,
                    flag, t | (l << 16), l == 0 ? 1 : 0);
            }
        }
    }

    out_gemm<<<NB * NS / 8, 256, 0, stream>>>(d_out, Wout, bout, flag);
    tail_kernel<<<(NL*NB*NH + 255)/256, 256, 0, stream>>>(st, d_out, flag);
}

// Round 4
// 38202.176 us; speedup vs baseline: 3.8345x; 1.4114x over previous
//
#include <hip/hip_runtime.h>
#include <hip/hip_bf16.h>

// MultilayerGRU: B=32 S=512 I=H=O=1024 L=3.
// Round 4: persistent pipeline, fast all-to-all flag barrier (no atomics),
// 512-thread WGs (2 waves/SIMD), register-hoisted A-frags, conflict-free
// LDS pitches, register-carried h_prev/biases in the epilogue.

#define NB 32
#define NS 512
#define NI 1024
#define NH 1024
#define NL 3
#define NO 1024

#define WGN 256
#define BLK 512
#define SLOTS 12
#define RPB 2096                 // weight row pitch bytes; 524 dwords == 12 mod 32 -> 2-way max (free)
#define ZROW 72                  // zero-row index
#define COFF (73 * RPB)          // 153,008
#define CPITCH 33                // 33 dwords == 1 mod 32 -> conflict-free
#define LDSB (COFF + 48 * CPITCH * 4)   // 159,344 <= 163,840

using short8 = __attribute__((ext_vector_type(8))) short;
using floatx4 = __attribute__((ext_vector_type(4))) float;

static __device__ __forceinline__ float bf2f(unsigned short u) {
    union { unsigned int i; float f; } v;
    v.i = ((unsigned int)u) << 16;
    return v.f;
}

static __device__ __forceinline__ unsigned short f2bf(float f) {
    __hip_bfloat16 h = __float2bfloat16(f);   // RNE
    union { __hip_bfloat16 h; unsigned short u; } v;
    v.h = h;
    return v.u;
}

static __device__ __forceinline__ void load8h(const unsigned short* p, float w[8]) {
    uint4 q = *(const uint4*)p;
    unsigned int u[4] = {q.x, q.y, q.z, q.w};
#pragma unroll
    for (int i = 0; i < 4; ++i) {
        w[2*i]   = __uint_as_float(u[i] << 16);
        w[2*i+1] = __uint_as_float(u[i] & 0xffff0000u);
    }
}

static __device__ __forceinline__ void load8f(const float* p, float w[8]) {
    float4 a = *(const float4*)p;
    float4 b = *(const float4*)(p + 4);
    w[0]=a.x; w[1]=a.y; w[2]=a.z; w[3]=a.w;
    w[4]=b.x; w[5]=b.y; w[6]=b.z; w[7]=b.w;
}

// ---------------- dtype detection ----------------
__global__ void detect_kernel(const unsigned int* __restrict__ xw, int* __restrict__ flag) {
    __shared__ int cnt[256];
    int c = 0;
    for (int i = threadIdx.x; i < 1024; i += 256) {
        unsigned int e = (xw[i] >> 7) & 0xFFu;
        if (e >= 0x78u && e <= 0x84u) c++;
    }
    cnt[threadIdx.x] = c;
    __syncthreads();
    if (threadIdx.x == 0) {
        int s = 0;
        for (int i = 0; i < 256; ++i) s += cnt[i];
        *flag = (s < 512) ? 1 : 0;
    }
}

// ---------------- init: h0 -> act parity-1 hi/lo; zero barrier flags ----
__global__ void init_act(const void* __restrict__ h0,
                         unsigned short* __restrict__ act_hi,
                         unsigned short* __restrict__ act_lo,
                         unsigned int* __restrict__ gflags,
                         const int* __restrict__ flagp) {
    const int f32m = *flagp;
    const int idx = blockIdx.x * 256 + threadIdx.x;  // l*32768 + b*1024 + j
    if (idx < WGN * 32) gflags[idx] = 0u;
    if (idx >= NL * NB * NH) return;
    const int l = idx >> 15;
    const int b = (idx >> 10) & 31;
    const int j = idx & 1023;
    const size_t src = (size_t)b * NL * NH + (size_t)l * NH + j;
    float v = f32m ? ((const float*)h0)[src] : bf2f(((const unsigned short*)h0)[src]);
    unsigned short hi = f2bf(v);
    unsigned short lo = f2bf(v - bf2f(hi));
    const size_t dst = ((size_t)(l * 2 + 1) * NB + b) * NH + j;   // parity 1
    act_hi[dst] = hi;
    act_lo[dst] = lo;
}

// ---------------- persistent pipeline kernel ----------------
__global__ __launch_bounds__(BLK, 1) void gru_persist(
    const void* __restrict__ x,
    const void* __restrict__ Wzi_, const void* __restrict__ Wzh_, const void* __restrict__ bzh_,
    const void* __restrict__ Wri_, const void* __restrict__ Wrh_, const void* __restrict__ brh_,
    const void* __restrict__ Wgi_, const void* __restrict__ Wgh_, const void* __restrict__ bgh_,
    void* __restrict__ dout,
    unsigned short* __restrict__ act_hi,
    unsigned short* __restrict__ act_lo,
    float* __restrict__ stfin,
    const int* __restrict__ flagp,
    unsigned int* __restrict__ gflags)
{
    extern __shared__ char lds[];
    float* clds = (float*)(lds + COFF);

    const int f32m = *flagp;
    const int tid  = threadIdx.x;
    const int wg   = blockIdx.x;
    const int lane = tid & 63;
    const int wid  = tid >> 6;          // 0..7
    const int Mtile = wid & 1;
    const int khalf = wid >> 1;         // 0..3 -> 256-col K slice
    const int n16  = lane & 15;
    const int q4   = lane >> 4;

    const int slot0 = wg * SLOTS;

    // ---- preload weights into LDS (bf16) ----
    {
        const void* Wmats[6] = {Wzi_, Wzh_, Wri_, Wrh_, Wgi_, Wgh_};
        if (f32m) {
            for (int idx = tid; idx < 72 * 256; idx += BLK) {
                const int r = idx >> 8, c4 = (idx & 255) * 4;
                const int slot = slot0 + r / 6, g = r % 6;
                const int layer = slot >> 10, j = slot & 1023;
                const float* src = (const float*)Wmats[g] + (size_t)layer * NH * NI + (size_t)j * NI + c4;
                float4 f = *(const float4*)src;
                unsigned short* dst = (unsigned short*)(lds + r * RPB + c4 * 2);
                dst[0] = f2bf(f.x); dst[1] = f2bf(f.y); dst[2] = f2bf(f.z); dst[3] = f2bf(f.w);
            }
        } else {
            for (int idx = tid; idx < 72 * 128; idx += BLK) {
                const int r = idx >> 7, c8 = (idx & 127) * 8;
                const int slot = slot0 + r / 6, g = r % 6;
                const int layer = slot >> 10, j = slot & 1023;
                const unsigned short* src = (const unsigned short*)Wmats[g] + (size_t)layer * NH * NI + (size_t)j * NI + c8;
                *(uint4*)(lds + r * RPB + c8 * 2) = *(const uint4*)src;
            }
        }
        unsigned int* z = (unsigned int*)(lds + ZROW * RPB);
        for (int c = tid; c < RPB / 4; c += BLK) z[c] = 0u;
    }

    // ---- epilogue thread state (tid < 384): biases + register h_prev ----
    int eci = 0, eb = 0, elg = 0, ej = 0;
    float ebz = 0.f, ebr = 0.f, ebg = 0.f, ehp = 0.f;
    if (tid < NB * SLOTS) {
        eci = tid % SLOTS; eb = tid / SLOTS;
        const int slot = slot0 + eci;
        elg = slot >> 10; ej = slot & 1023;
        const size_t bidx = (size_t)elg * NH + ej;
        if (f32m) {
            ebz = ((const float*)bzh_)[bidx];
            ebr = ((const float*)brh_)[bidx];
            ebg = ((const float*)bgh_)[bidx];
        } else {
            ebz = bf2f(((const unsigned short*)bzh_)[bidx]);
            ebr = bf2f(((const unsigned short*)brh_)[bidx]);
            ebg = bf2f(((const unsigned short*)bgh_)[bidx]);
        }
    }

    // ---- layer groups (slot range may straddle one layer boundary) ----
    const int lay0 = slot0 >> 10;
    const int lay1 = (slot0 + SLOTS - 1) >> 10;
    const int ngroups = (lay0 == lay1) ? 1 : 2;
    const int n0 = (ngroups == 1) ? SLOTS : (1024 - (slot0 & 1023));

    __syncthreads();

    for (int s = 0; s < NS + NL - 1; ++s) {
        for (int i = tid; i < 48 * CPITCH; i += BLK) clds[i] = 0.f;
        __syncthreads();

        floatx4 acc[3];
#pragma unroll
        for (int nt = 0; nt < 3; ++nt) acc[nt] = (floatx4){0.f, 0.f, 0.f, 0.f};

        for (int grp = 0; grp < ngroups; ++grp) {
            const int lg = (grp == 0) ? lay0 : lay1;
            const int t = s - lg;
            if (t < 0 || t >= NS) continue;
            const int ntLo = (grp == 0) ? 0 : ((4 * n0) >> 4);
            const int ntHi = (grp == 0) ? (ngroups == 1 ? 2 : ((4 * n0) >> 4) - 1) : 2;
            const int mb = Mtile * 16 + n16;

            for (int phase = 0; phase < 2; ++phase) {
                int brow[3];
#pragma unroll
                for (int nt = 0; nt < 3; ++nt) {
                    const int v = nt * 16 + n16;
                    const int ci = v >> 2, g = v & 3;
                    int r;
                    if (phase == 0) r = (g == 3) ? ZROW : ci * 6 + ((g == 2) ? 4 : g * 2);
                    else            r = (g == 2) ? ZROW : ci * 6 + ((g == 3) ? 5 : g * 2 + 1);
                    brow[nt] = r;
                }

                const bool isx = (phase == 0 && lg == 0);
                const bool dolo = isx ? (f32m != 0) : true;

                // hoist all A-frags for this phase into registers
                short8 AH[8], AL[8];
                if (isx) {
                    if (f32m) {
                        const float* xb = (const float*)x + ((size_t)mb * NS + t) * NI + khalf * 256 + q4 * 8;
#pragma unroll
                        for (int ks = 0; ks < 8; ++ks) {
                            float f[8];
                            load8f(xb + ks * 32, f);
#pragma unroll
                            for (int e = 0; e < 8; ++e) {
                                unsigned short h = f2bf(f[e]);
                                AH[ks][e] = (short)h;
                                AL[ks][e] = (short)f2bf(f[e] - bf2f(h));
                            }
                        }
                    } else {
                        const unsigned short* xb = (const unsigned short*)x + ((size_t)mb * NS + t) * NI + khalf * 256 + q4 * 8;
#pragma unroll
                        for (int ks = 0; ks < 8; ++ks)
                            AH[ks] = *(const short8*)(xb + ks * 32);
                    }
                } else {
                    const int src_l = (phase == 0) ? lg - 1 : lg;
                    const int src_p = (phase == 0) ? (t & 1) : ((t - 1) & 1);
                    const size_t ab = ((size_t)(src_l * 2 + src_p) * NB + mb) * NH + khalf * 256 + q4 * 8;
                    const unsigned short* ah = act_hi + ab;
                    const unsigned short* al = act_lo + ab;
#pragma unroll
                    for (int ks = 0; ks < 8; ++ks) {
                        AH[ks] = *(const short8*)(ah + ks * 32);
                        AL[ks] = *(const short8*)(al + ks * 32);
                    }
                }

#pragma unroll
                for (int ks = 0; ks < 8; ++ks) {
                    const int k0 = khalf * 256 + ks * 32;
#pragma unroll
                    for (int nt = 0; nt < 3; ++nt) {
                        if (nt < ntLo || nt > ntHi) continue;
                        const short8 bf = *(const short8*)(lds + brow[nt] * RPB + k0 * 2 + q4 * 16);
                        acc[nt] = __builtin_amdgcn_mfma_f32_16x16x32_bf16(AH[ks], bf, acc[nt], 0, 0, 0);
                        if (dolo)
                            acc[nt] = __builtin_amdgcn_mfma_f32_16x16x32_bf16(AL[ks], bf, acc[nt], 0, 0, 0);
                    }
                }
            }
        }

        // dump accumulators (C/D: col=lane&15, row=q4*4+reg)
        {
            const int mbase = Mtile * 16 + q4 * 4;
#pragma unroll
            for (int nt = 0; nt < 3; ++nt) {
                const int vcol = nt * 16 + n16;
#pragma unroll
                for (int r = 0; r < 4; ++r)
                    atomicAdd(&clds[vcol * CPITCH + mbase + r], acc[nt][r]);
            }
        }
        __syncthreads();

        // epilogue: one thread per (col, batch)
        if (tid < NB * SLOTS) {
            const int t = s - elg;
            if (t >= 0 && t < NS) {
                const float zp = clds[(eci * 4 + 0) * CPITCH + eb];
                const float rp = clds[(eci * 4 + 1) * CPITCH + eb];
                const float gi = clds[(eci * 4 + 2) * CPITCH + eb];
                const float gh = clds[(eci * 4 + 3) * CPITCH + eb];
                float hp;
                if (t == 0) {
                    const size_t hoff = ((size_t)(elg * 2 + 1) * NB + eb) * NH + ej;
                    hp = bf2f(act_hi[hoff]) + bf2f(act_lo[hoff]);
                } else {
                    hp = ehp;
                }
                const float z = 1.f / (1.f + expf(-(zp + ebz)));
                const float r = 1.f / (1.f + expf(-(rp + ebr)));
                const float g = tanhf(gi + r * (gh + ebg));
                const float hn = z * hp + (1.f - z) * g;
                ehp = hn;
                const unsigned short hi = f2bf(hn);
                const unsigned short lo = f2bf(hn - bf2f(hi));
                const size_t woff = ((size_t)(elg * 2 + (t & 1)) * NB + eb) * NH + ej;
                act_hi[woff] = hi;
                act_lo[woff] = lo;
                if (elg == 2) {
                    const size_t o = ((size_t)eb * NS + t) * NO + ej;
                    if (f32m) ((float*)dout)[o] = hn;
                    else      ((unsigned short*)dout)[o] = f2bf(hn);
                }
                if (t == NS - 1)
                    stfin[((size_t)elg * NB + eb) * NH + ej] = hn;
            }
        }

        // ---- all-to-all flag barrier: no atomic RMW, no shared-line contention ----
        __syncthreads();
        __threadfence();      // every wave drains/publishes its own stores
        if (tid == 0)
            __hip_atomic_store(&gflags[wg * 32], (unsigned int)(s + 1),
                               __ATOMIC_RELEASE, __HIP_MEMORY_SCOPE_AGENT);
        if (tid < WGN) {
            while (__hip_atomic_load(&gflags[tid * 32], __ATOMIC_ACQUIRE,
                                     __HIP_MEMORY_SCOPE_AGENT) <= (unsigned int)s)
                __builtin_amdgcn_s_sleep(2);
        }
        __syncthreads();
    }
}

// ---------------- fallback kernels (round-2, proven) ----------------
__global__ void init_kernel(const void* __restrict__ h0, float* __restrict__ st,
                            const int* __restrict__ flagp) {
    const int f32m = *flagp;
    const int idx = blockIdx.x * 256 + threadIdx.x;
    if (idx >= NL * NB * NH) return;
    const int l = idx >> 15;
    const int b = (idx >> 10) & 31;
    const int j = idx & 1023;
    const size_t src = (size_t)b * NL * NH + (size_t)l * NH + j;
    st[idx] = f32m ? ((const float*)h0)[src] : bf2f(((const unsigned short*)h0)[src]);
}

__global__ __launch_bounds__(256) void gru_layer(
    const void*  __restrict__ x,
    const float* __restrict__ inp,
    const float* __restrict__ hprev,
    float*       __restrict__ hnew,
    void*        __restrict__ h2out,
    const void* __restrict__ Wzi_, const void* __restrict__ Wzh_, const void* __restrict__ bzh_,
    const void* __restrict__ Wri_, const void* __restrict__ Wrh_, const void* __restrict__ brh_,
    const void* __restrict__ Wgi_, const void* __restrict__ Wgh_, const void* __restrict__ bgh_,
    const int* __restrict__ flagp, int tl, int isX)
{
    __shared__ float s_in[NB][129];
    __shared__ float s_h [NB][129];
    __shared__ float s_red[256][6];

    const int f32m = *flagp;
    const int t = tl & 0xFFFF;
    const int l = tl >> 16;
    const int tid = threadIdx.x;
    const int b   = tid & 31;
    const int jl  = (tid >> 5) & 1;
    const int ks  = tid >> 6;
    const int j   = blockIdx.x * 2 + jl;

    const size_t wIl = (size_t)l * NH * NI + (size_t)j * NI;
    const size_t bl  = (size_t)l * NH + j;

    float azi = 0.f, azh = 0.f, ari = 0.f, arh = 0.f, agi = 0.f, agh = 0.f;

    for (int kc = 0; kc < 8; ++kc) {
        const int k0 = kc * 128;
        __syncthreads();
        for (int idx = tid; idx < NB * 128; idx += 256) {
            const int r = idx >> 7, c = idx & 127;
            float vi;
            if (isX) {
                const size_t xo = (size_t)r * NS * NI + (size_t)t * NI + (k0 + c);
                vi = f32m ? ((const float*)x)[xo] : bf2f(((const unsigned short*)x)[xo]);
            } else {
                vi = inp[r * NH + k0 + c];
            }
            s_in[r][c] = vi;
            s_h [r][c] = hprev[r * NH + k0 + c];
        }
        __syncthreads();

        const int cbase = ks * 32;
#pragma unroll
        for (int q8 = 0; q8 < 4; ++q8) {
            const int c = cbase + q8 * 8;
            const int k = k0 + c;
            float wz[8], wr[8], wg[8], vz[8], vr[8], vg[8];
            if (f32m) {
                load8f((const float*)Wzi_ + wIl + k, wz);
                load8f((const float*)Wri_ + wIl + k, wr);
                load8f((const float*)Wgi_ + wIl + k, wg);
                load8f((const float*)Wzh_ + wIl + k, vz);
                load8f((const float*)Wrh_ + wIl + k, vr);
                load8f((const float*)Wgh_ + wIl + k, vg);
            } else {
                load8h((const unsigned short*)Wzi_ + wIl + k, wz);
                load8h((const unsigned short*)Wri_ + wIl + k, wr);
                load8h((const unsigned short*)Wgi_ + wIl + k, wg);
                load8h((const unsigned short*)Wzh_ + wIl + k, vz);
                load8h((const unsigned short*)Wrh_ + wIl + k, vr);
                load8h((const unsigned short*)Wgh_ + wIl + k, vg);
            }
            float ai[8], ah[8];
#pragma unroll
            for (int q = 0; q < 8; ++q) { ai[q] = s_in[b][c + q]; ah[q] = s_h[b][c + q]; }
#pragma unroll
            for (int q = 0; q < 8; ++q) {
                azi = fmaf(wz[q], ai[q], azi);
                ari = fmaf(wr[q], ai[q], ari);
                agi = fmaf(wg[q], ai[q], agi);
                azh = fmaf(vz[q], ah[q], azh);
                arh = fmaf(vr[q], ah[q], arh);
                agh = fmaf(vg[q], ah[q], agh);
            }
        }
    }

    s_red[tid][0] = azi; s_red[tid][1] = azh; s_red[tid][2] = ari;
    s_red[tid][3] = arh; s_red[tid][4] = agi; s_red[tid][5] = agh;
    __syncthreads();

    if (ks == 0) {
#pragma unroll
        for (int w = 1; w < 4; ++w) {
            azi += s_red[tid + 64*w][0]; azh += s_red[tid + 64*w][1];
            ari += s_red[tid + 64*w][2]; arh += s_red[tid + 64*w][3];
            agi += s_red[tid + 64*w][4]; agh += s_red[tid + 64*w][5];
        }
        const float bz = f32m ? ((const float*)bzh_)[bl] : bf2f(((const unsigned short*)bzh_)[bl]);
        const float br = f32m ? ((const float*)brh_)[bl] : bf2f(((const unsigned short*)brh_)[bl]);
        const float bg = f32m ? ((const float*)bgh_)[bl] : bf2f(((const unsigned short*)bgh_)[bl]);
        const float z = 1.f / (1.f + expf(-(azi + azh + bz)));
        const float r = 1.f / (1.f + expf(-(ari + arh + br)));
        const float g = tanhf(agi + r * (agh + bg));
        const float hp = hprev[b * NH + j];
        const float hn = z * hp + (1.f - z) * g;
        hnew[b * NH + j] = hn;
        if (h2out) {
            const size_t off = (size_t)b * NS * NO + (size_t)t * NO + j;
            if (f32m) ((float*)h2out)[off] = hn;
            else      ((unsigned short*)h2out)[off] = f2bf(hn);
        }
    }
}

__global__ __launch_bounds__(256) void out_gemm(
    void* __restrict__ out, const void* __restrict__ Wout, const void* __restrict__ bout,
    const int* __restrict__ flagp)
{
    __shared__ float s_a[8][1024];
    const int f32m = *flagp;
    const int tid = threadIdx.x;
    const size_t row0 = (size_t)blockIdx.x * 8;

    for (int idx = tid; idx < 8 * 1024; idx += 256) {
        const int r = idx >> 10, c = idx & 1023;
        const size_t off = (row0 + r) * NO + c;
        s_a[r][c] = f32m ? ((const float*)out)[off] : bf2f(((const unsigned short*)out)[off]);
    }
    __syncthreads();

    float acc[4][8];
#pragma unroll
    for (int m = 0; m < 4; ++m)
#pragma unroll
        for (int r = 0; r < 8; ++r) acc[m][r] = 0.f;

    for (int k8 = 0; k8 < 128; ++k8) {
        const int k = k8 * 8;
        float wf[4][8];
#pragma unroll
        for (int m = 0; m < 4; ++m) {
            const size_t wo = (size_t)(tid + 256*m) * NH + k;
            if (f32m) load8f((const float*)Wout + wo, wf[m]);
            else      load8h((const unsigned short*)Wout + wo, wf[m]);
        }
#pragma unroll
        for (int r = 0; r < 8; ++r) {
            float a[8];
#pragma unroll
            for (int q = 0; q < 8; ++q) a[q] = s_a[r][k + q];
#pragma unroll
            for (int m = 0; m < 4; ++m)
#pragma unroll
                for (int q = 0; q < 8; ++q)
                    acc[m][r] = fmaf(wf[m][q], a[q], acc[m][r]);
        }
    }

#pragma unroll
    for (int m = 0; m < 4; ++m) {
        const int jj = tid + 256*m;
        const float bj = f32m ? ((const float*)bout)[jj] : bf2f(((const unsigned short*)bout)[jj]);
#pragma unroll
        for (int r = 0; r < 8; ++r) {
            const size_t off = (row0 + r) * NO + jj;
            const float v = acc[m][r] + bj;
            if (f32m) ((float*)out)[off] = v;
            else      ((unsigned short*)out)[off] = f2bf(v);
        }
    }
}

__global__ void tail_kernel(const float* __restrict__ st, void* __restrict__ out,
                            const int* __restrict__ flagp)
{
    const int f32m = *flagp;
    const int idx = blockIdx.x * 256 + threadIdx.x;
    if (idx >= NL * NB * NH) return;
    const int l = idx >> 15;
    const int b = (idx >> 10) & 31;
    const int j = idx & 1023;
    const size_t dst = (size_t)NB * NS * NO + (size_t)b * NL * NH + (size_t)l * NH + j;
    if (f32m) ((float*)out)[dst] = st[idx];
    else      ((unsigned short*)out)[dst] = f2bf(st[idx]);
}

// ---------------- host ----------------
extern "C" void kernel_launch(void* const* d_in, const int* in_sizes, int n_in,
                              void* d_out, int out_size, void* d_ws, size_t ws_size,
                              hipStream_t stream)
{
    const void* x    = d_in[0];
    const void* h0   = d_in[1];
    const void* Wzi  = d_in[2];
    const void* Wzh  = d_in[3];
    const void* bzh  = d_in[4];
    const void* Wri  = d_in[5];
    const void* Wrh  = d_in[6];
    const void* brh  = d_in[7];
    const void* Wgi  = d_in[8];
    const void* Wgh  = d_in[9];
    const void* bgh  = d_in[10];
    const void* Wout = d_in[11];
    const void* bout = d_in[12];

    // ws layout
    char* w = (char*)d_ws;
    float* st            = (float*)w;                       // [2][3][32][1024] f32
    int*   flag          = (int*)(w + 786432);
    unsigned short* ahi  = (unsigned short*)(w + 786464);   // [3][2][32][1024] bf16
    unsigned short* alo  = ahi + (size_t)NL * 2 * NB * NH;  // ends at 1,572,896
    unsigned int* gflags = (unsigned int*)(w + 1572992);    // 256 x 128B, ends 1,605,760
    auto stp = [&](int p, int l) { return st + ((size_t)(p * NL + l)) * NB * NH; };

    detect_kernel<<<1, 256, 0, stream>>>((const unsigned int*)x, flag);
    init_act<<<(NL*NB*NH + 255)/256, 256, 0, stream>>>(h0, ahi, alo, gflags, flag);

    (void)hipFuncSetAttribute((const void*)gru_persist,
                              hipFuncAttributeMaxDynamicSharedMemorySize, LDSB);
    (void)hipGetLastError();   // clear
    gru_persist<<<WGN, BLK, LDSB, stream>>>(
        x, Wzi, Wzh, bzh, Wri, Wrh, brh, Wgi, Wgh, bgh,
        d_out, ahi, alo, st /* final h at parity0 */, flag, gflags);
    hipError_t perr = hipGetLastError();

    if (perr != hipSuccess) {
        init_kernel<<<(NL*NB*NH + 255)/256, 256, 0, stream>>>(h0, st, flag);
        for (int t = 0; t < NS; ++t) {
            const int pr = t & 1, pw = 1 - pr;
            for (int l = 0; l < NL; ++l) {
                gru_layer<<<512, 256, 0, stream>>>(
                    x,
                    l == 0 ? st : stp(pw, l - 1),
                    stp(pr, l),
                    stp(pw, l),
                    l == 2 ? d_out : (void*)nullptr,
                    Wzi, Wzh, bzh, Wri, Wrh, brh, Wgi, Wgh, bgh,
                    flag, t | (l << 16), l == 0 ? 1 : 0);
            }
        }
    }

    out_gemm<<<NB * NS / 8, 256, 0, stream>>>(d_out, Wout, bout, flag);
    tail_kernel<<<(NL*NB*NH + 255)/256, 256, 0, stream>>>(st, d_out, flag);
}